// Round 1
// baseline (284.203 us; speedup 1.0000x reference)
//
#include <hip/hip_runtime.h>
#include <hip/hip_bf16.h>
#include <math.h>

// MultiHeadAttention: B=2, S=2048, D=1024, H=16, HD=64
// Pipeline: fp32->bf16 convert | QKV GEMM (MFMA bf16) | flash attention (MFMA bf16)

typedef __bf16 bf16_t;
typedef __attribute__((ext_vector_type(8))) __bf16 bf16x8;
typedef __attribute__((ext_vector_type(4))) __bf16 bf16x4;
typedef __attribute__((ext_vector_type(4))) float f32x4;

#define B_  2
#define S_  2048
#define D_  1024
#define H_  16
#define HD_ 64
#define M_  (B_ * S_)   // 4096
#define K_  D_          // 1024

__device__ __forceinline__ f32x4 mfma16x16x32(bf16x8 a, bf16x8 b, f32x4 c) {
    return __builtin_amdgcn_mfma_f32_16x16x32_bf16(a, b, c, 0, 0, 0);
}

__device__ __forceinline__ void gload_lds16(const bf16_t* g, bf16_t* l) {
    __builtin_amdgcn_global_load_lds(
        (const __attribute__((address_space(1))) void*)g,
        (__attribute__((address_space(3))) void*)l,
        16, 0, 0);
}

// ---------------------------------------------------------------- conversion
__global__ void cvt_f32_bf16(const float* __restrict__ src,
                             bf16_t* __restrict__ dst, int n4) {
    int i = blockIdx.x * blockDim.x + threadIdx.x;
    if (i >= n4) return;
    float4 v = ((const float4*)src)[i];
    bf16x4 o;
    o[0] = (bf16_t)v.x; o[1] = (bf16_t)v.y;
    o[2] = (bf16_t)v.z; o[3] = (bf16_t)v.w;
    ((bf16x4*)dst)[i] = o;
}

// ---------------------------------------------------------------- QKV GEMM
// Y[m][n] = sum_k X[m][k] * W[n][k] + bias[n]   (both row-major [rows][K])
// z=0 -> Q [B][H][S][HD], z=1 -> K same, z=2 -> V transposed [B][H][HD][S]
__global__ __launch_bounds__(256, 2)
void gemm_qkv(const bf16_t* __restrict__ Xb, const bf16_t* __restrict__ Wb3,
              const float* __restrict__ bq, const float* __restrict__ bk,
              const float* __restrict__ bv,
              bf16_t* __restrict__ Qo, bf16_t* __restrict__ Ko,
              bf16_t* __restrict__ Vt) {
    __shared__ bf16_t smem[8192];           // A tile 128x32 | B tile 128x32 (16 KB)
    const int z = blockIdx.z;
    const bf16_t* Wb = Wb3 + (size_t)z * (D_ * K_);
    const float* bias = (z == 0) ? bq : (z == 1) ? bk : bv;

    const int tid  = threadIdx.x;
    const int lane = tid & 63;
    const int w    = tid >> 6;
    const int wr   = w >> 1, wc = w & 1;
    const int m0   = blockIdx.y * 128;
    const int n0   = blockIdx.x * 128;

    f32x4 acc[4][4];
    const f32x4 fzero = {0.f, 0.f, 0.f, 0.f};
#pragma unroll
    for (int i = 0; i < 4; i++)
#pragma unroll
        for (int j = 0; j < 4; j++) acc[i][j] = fzero;

    const int koff = (lane >> 4) * 8;

    for (int k0 = 0; k0 < K_; k0 += 32) {
        // stage 16 KB: 16 chunks of 1 KB; wave w owns chunks w*4 .. w*4+3
#pragma unroll
        for (int i = 0; i < 4; i++) {
            const int chunk  = w * 4 + i;
            const int byteoff = chunk * 1024 + lane * 16;
            bf16_t* ldst = &smem[chunk * 512];          // wave-uniform base
            const bf16_t* gsrc;
            if (byteoff < 8192) {                        // A region
                int row = byteoff >> 6;                  // 64 B per row (32 bf16)
                int col = (byteoff & 63) >> 1;
                gsrc = Xb + (size_t)(m0 + row) * K_ + k0 + col;
            } else {                                     // B region
                int bo  = byteoff - 8192;
                int row = bo >> 6;
                int col = (bo & 63) >> 1;
                gsrc = Wb + (size_t)(n0 + row) * K_ + k0 + col;
            }
            gload_lds16(gsrc, ldst);
        }
        __syncthreads();

        bf16x8 af[4], bfr[4];
#pragma unroll
        for (int m = 0; m < 4; m++) {
            int row = wr * 64 + m * 16 + (lane & 15);
            af[m] = *(const bf16x8*)&smem[row * 32 + koff];
        }
#pragma unroll
        for (int n = 0; n < 4; n++) {
            int row = wc * 64 + n * 16 + (lane & 15);
            bfr[n] = *(const bf16x8*)&smem[4096 + row * 32 + koff];
        }
#pragma unroll
        for (int m = 0; m < 4; m++)
#pragma unroll
            for (int n = 0; n < 4; n++)
                acc[m][n] = mfma16x16x32(af[m], bfr[n], acc[m][n]);
        __syncthreads();
    }

    // epilogue: bias add, cast, scatter to attention-friendly layouts
#pragma unroll
    for (int m = 0; m < 4; m++) {
        const int gm    = m0 + wr * 64 + m * 16 + ((lane >> 4) << 2);
        const int bidx  = gm >> 11;        // / 2048
        const int sbase = gm & 2047;
#pragma unroll
        for (int n = 0; n < 4; n++) {
            const int gn = n0 + wc * 64 + n * 16 + (lane & 15);
            const int h  = gn >> 6, hd = gn & 63;
            const float bias_v = bias[gn];
#pragma unroll
            for (int j = 0; j < 4; j++) {
                float y = acc[m][n][j] + bias_v;
                bf16_t yb = (bf16_t)y;
                if (z == 2) {
                    Vt[(((size_t)bidx * H_ + h) * HD_ + hd) * S_ + sbase + j] = yb;
                } else {
                    bf16_t* O = (z == 0) ? Qo : Ko;
                    O[(((size_t)bidx * H_ + h) * S_ + sbase + j) * HD_ + hd] = yb;
                }
            }
        }
    }
}

// ---------------------------------------------------------------- attention
// grid (32 qtiles, 16 heads, 2 batch); 4 waves x 16 Q-rows each.
__global__ __launch_bounds__(256, 2)
void attn_fwd(const bf16_t* __restrict__ Qb, const bf16_t* __restrict__ Kb,
              const bf16_t* __restrict__ Vt, const float* __restrict__ mask,
              float* __restrict__ out) {
    const int qt = blockIdx.x, h = blockIdx.y, b = blockIdx.z;
    const int tid = threadIdx.x, lane = tid & 63, w = tid >> 6;
    const int bh = b * H_ + h;
    const bf16_t* Qh = Qb + (size_t)bh * S_ * HD_;
    const bf16_t* Kh = Kb + (size_t)bh * S_ * HD_;
    const bf16_t* Vh = Vt + (size_t)bh * HD_ * S_;
    const float*  mk = mask + (size_t)b * S_;

    __shared__ bf16_t Plds[4][16][80];   // per-wave 16x64 P tile, stride 80 (16B-aligned rows)

    const int koff = (lane >> 4) * 8;
    const int qrow = qt * 64 + w * 16 + (lane & 15);
    const bf16x8 qf0 = *(const bf16x8*)(Qh + (size_t)qrow * HD_ + koff);
    const bf16x8 qf1 = *(const bf16x8*)(Qh + (size_t)qrow * HD_ + 32 + koff);

    const f32x4 fzero = {0.f, 0.f, 0.f, 0.f};
    f32x4 of[4];
#pragma unroll
    for (int i = 0; i < 4; i++) of[i] = fzero;
    float mrun[4] = {-INFINITY, -INFINITY, -INFINITY, -INFINITY};
    float lsum[4] = {0.f, 0.f, 0.f, 0.f};
    const float scale = 0.125f;          // 1/sqrt(64)

    for (int kv0 = 0; kv0 < S_; kv0 += 64) {
        // ---- scores S = Q K^T / 8 + mask
        f32x4 sc[4];
#pragma unroll
        for (int nb = 0; nb < 4; nb++) {
            const int krow = kv0 + nb * 16 + (lane & 15);
            bf16x8 kf0 = *(const bf16x8*)(Kh + (size_t)krow * HD_ + koff);
            bf16x8 kf1 = *(const bf16x8*)(Kh + (size_t)krow * HD_ + 32 + koff);
            f32x4 t = fzero;
            t = mfma16x16x32(qf0, kf0, t);
            t = mfma16x16x32(qf1, kf1, t);
            sc[nb] = t;
        }
        float mv[4];
#pragma unroll
        for (int nb = 0; nb < 4; nb++)
            mv[nb] = mk[kv0 + nb * 16 + (lane & 15)];
#pragma unroll
        for (int nb = 0; nb < 4; nb++)
#pragma unroll
            for (int j = 0; j < 4; j++)
                sc[nb][j] = sc[nb][j] * scale + mv[nb];

        // ---- online softmax (rows = (lane>>4)*4+j, replicated over 16 lanes)
        float tmax[4];
#pragma unroll
        for (int j = 0; j < 4; j++) {
            tmax[j] = fmaxf(fmaxf(sc[0][j], sc[1][j]), fmaxf(sc[2][j], sc[3][j]));
#pragma unroll
            for (int off = 8; off >= 1; off >>= 1)
                tmax[j] = fmaxf(tmax[j], __shfl_xor(tmax[j], off, 64));
        }
        float mnew[4], alpha[4];
#pragma unroll
        for (int j = 0; j < 4; j++) {
            mnew[j]  = fmaxf(mrun[j], tmax[j]);
            alpha[j] = __expf(mrun[j] - mnew[j]);
            mrun[j]  = mnew[j];
            lsum[j] *= alpha[j];
#pragma unroll
            for (int db = 0; db < 4; db++) of[db][j] *= alpha[j];
        }

        // ---- P = exp(S - m), transpose via LDS for PV A-fragment
        __syncthreads();   // previous iteration's P reads complete before overwrite
#pragma unroll
        for (int nb = 0; nb < 4; nb++)
#pragma unroll
            for (int j = 0; j < 4; j++) {
                float p = __expf(sc[nb][j] - mnew[j]);
                lsum[j] += p;
                Plds[w][(lane >> 4) * 4 + j][nb * 16 + (lane & 15)] = (bf16_t)p;
            }
        __syncthreads();
        bf16x8 pa0 = *(const bf16x8*)&Plds[w][lane & 15][koff];
        bf16x8 pa1 = *(const bf16x8*)&Plds[w][lane & 15][32 + koff];

        // ---- O += P V   (V^T rows are contiguous in kv)
#pragma unroll
        for (int db = 0; db < 4; db++) {
            const bf16_t* vrow = Vh + (size_t)(db * 16 + (lane & 15)) * S_ + kv0;
            bf16x8 vf0 = *(const bf16x8*)(vrow + koff);
            bf16x8 vf1 = *(const bf16x8*)(vrow + 32 + koff);
            of[db] = mfma16x16x32(pa0, vf0, of[db]);
            of[db] = mfma16x16x32(pa1, vf1, of[db]);
        }
    }

    // ---- finalize: denominator across the 16-lane column group, write fp32
#pragma unroll
    for (int j = 0; j < 4; j++) {
#pragma unroll
        for (int off = 8; off >= 1; off >>= 1)
            lsum[j] += __shfl_xor(lsum[j], off, 64);
    }
    float inv[4];
#pragma unroll
    for (int j = 0; j < 4; j++) inv[j] = 1.0f / lsum[j];
#pragma unroll
    for (int db = 0; db < 4; db++) {
        const int d = h * HD_ + db * 16 + (lane & 15);
#pragma unroll
        for (int j = 0; j < 4; j++) {
            const int row = qt * 64 + w * 16 + (lane >> 4) * 4 + j;
            out[((size_t)b * S_ + row) * D_ + d] = of[db][j] * inv[j];
        }
    }
}

// ---------------------------------------------------------------- launch
extern "C" void kernel_launch(void* const* d_in, const int* in_sizes, int n_in,
                              void* d_out, int out_size, void* d_ws, size_t ws_size,
                              hipStream_t stream) {
    const float* hs   = (const float*)d_in[0];
    const float* mask = (const float*)d_in[1];
    const float* Wq   = (const float*)d_in[2];
    const float* bq   = (const float*)d_in[3];
    const float* Wk   = (const float*)d_in[4];
    const float* bk   = (const float*)d_in[5];
    const float* Wv   = (const float*)d_in[6];
    const float* bv   = (const float*)d_in[7];
    float* out = (float*)d_out;

    char* ws = (char*)d_ws;
    bf16_t* Xb  = (bf16_t*)(ws);                    //  8,388,608 B  [4096][1024]
    bf16_t* Wb3 = (bf16_t*)(ws + 8388608);          //  6,291,456 B  3x[1024][1024]
    bf16_t* Qb  = (bf16_t*)(ws + 14680064);         //  8,388,608 B  [B][H][S][HD]
    bf16_t* Kb  = (bf16_t*)(ws + 23068672);         //  8,388,608 B  [B][H][S][HD]
    bf16_t* Vt  = (bf16_t*)(ws + 31457280);         //  8,388,608 B  [B][H][HD][S]

    const int nX4 = (M_ * K_) / 4;                  // 1,048,576
    const int nW4 = (D_ * K_) / 4;                  //   262,144
    cvt_f32_bf16<<<nX4 / 256, 256, 0, stream>>>(hs, Xb, nX4);
    cvt_f32_bf16<<<nW4 / 256, 256, 0, stream>>>(Wq, Wb3, nW4);
    cvt_f32_bf16<<<nW4 / 256, 256, 0, stream>>>(Wk, Wb3 + D_ * K_, nW4);
    cvt_f32_bf16<<<nW4 / 256, 256, 0, stream>>>(Wv, Wb3 + 2 * D_ * K_, nW4);

    dim3 ggrid(D_ / 128, M_ / 128, 3);              // (8, 32, 3)
    gemm_qkv<<<ggrid, 256, 0, stream>>>(Xb, Wb3, bq, bk, bv, Qb, Kb, Vt);

    dim3 agrid(S_ / 64, H_, B_);                    // (32, 16, 2)
    attn_fwd<<<agrid, 256, 0, stream>>>(Qb, Kb, Vt, mask, out);
}